// Round 1
// 233.126 us; speedup vs baseline: 1.1055x; 1.1055x over previous
//
#include <hip/hip_runtime.h>

// LSTM RNN: B=2048, L=256 (257 scan steps), F=64, H=32, K=2.
// R3: A-row dup pattern [0,0,0,0,1,1,1,1,...]: lane-group q owns batch q in ALL
//     4 acc elements -> no z cndmask-select; token bit = (spt>>q)&1 (1 per lane);
//     softplus 1x per rr lane-group instead of 4x.
//     Gate columns of Wh/Bx/b_lstm pre-scaled by -L2E (i,f,o) / -2*L2E (g): the
//     MFMA emits the exp2 argument directly (sigma = rcp(1+exp2(y))).
//     h -> bf16 via v_cvt_pk_bf16_f32 (1 op RNE). Loop unrolled x2, rb static.
// h exchange: 640B double buffer, b-stride 160B (<=2-way banks, 16B aligned).

typedef __attribute__((ext_vector_type(8))) short bf16x8;
typedef __attribute__((ext_vector_type(4))) float f32x4;

#define L2E 1.44269504088896340736f
#define LN2 0.69314718055994530942f

__device__ __forceinline__ short f2bf(float x) {
    unsigned u = __builtin_bit_cast(unsigned, x);
    unsigned r = (u + 0x7FFFu + ((u >> 16) & 1u)) >> 16;
    return (short)r;
}

__global__ __launch_bounds__(256) void lstm_kernel(
    const int* __restrict__ s, const float* __restrict__ g,
    const float* __restrict__ W_emb, const float* __restrict__ b_emb,
    const float* __restrict__ W_g1, const float* __restrict__ b_g1,
    const float* __restrict__ W_g2, const float* __restrict__ b_g2,
    const float* __restrict__ W_gh, const float* __restrict__ b_gh,
    const float* __restrict__ W_gc, const float* __restrict__ b_gc,
    const float* __restrict__ Wi, const float* __restrict__ Wh,
    const float* __restrict__ b_lstm, const float* __restrict__ W_amp,
    const float* __restrict__ b_amp, float* __restrict__ out)
{
    __shared__ float Bx[35 * 256];              // 0-31: W_g2@Wi; 32-33: W_emb@Wi; 34: const (all pre-scaled)
    __shared__ unsigned char sp_l[260];         // packed tokens: bit b of sp_l[t] = s_pad[b][t]
    __shared__ __align__(16) short Hb[2][320];  // h dbuf: [b(4) * 80 + f(64)] bf16
    __shared__ float red[4][4];                 // per-wave logp partials

    const int tid = threadIdx.x;
    const int w   = tid >> 6;     // wave 0..3
    const int l   = tid & 63;     // lane
    const int n2  = l & 15;       // MFMA col
    const int q   = l >> 4;       // MFMA k-quad == owned batch row
    const int wgb = blockIdx.x * 4;

    // ---------- Setup: folded B rows into LDS, pre-scaled by activation constants ----------
    {
        const int n = tid;
        // cols [0,64)=i, [64,128)=f: sigmoid -> -L2E; [128,192)=g: tanh -> -2*L2E; [192,256)=o: -L2E
        const float sc = (n >= 128 && n < 192) ? (-2.0f * L2E) : (-L2E);
        float acc[35];
        #pragma unroll
        for (int i = 0; i < 35; ++i) acc[i] = 0.f;
        for (int f = 0; f < 64; ++f) {
            float wi = Wi[f * 256 + n] * sc;
            #pragma unroll
            for (int k = 0; k < 32; ++k) acc[k] += W_g2[k * 64 + f] * wi;  // uniform
            acc[32] += W_emb[f] * wi;
            acc[33] += W_emb[64 + f] * wi;
            acc[34] += (b_emb[f] + b_g2[f]) * wi;
        }
        acc[34] += b_lstm[n] * sc;
        #pragma unroll
        for (int i = 0; i < 35; ++i) Bx[i * 256 + n] = acc[i];
    }
    // token staging: sp_l[t+1] bits = s[:, t], sp_l[0] = 0
    {
        unsigned v = 0;
        #pragma unroll
        for (int b = 0; b < 4; ++b)
            v |= (unsigned)(s[(wgb + b) * 256 + tid] & 1) << b;
        sp_l[tid + 1] = (unsigned char)v;
        if (tid == 0) sp_l[0] = 0;
    }
    __syncthreads();

    // ---------- static fragments ----------
    bf16x8 Bf[4][2];          // Wh (K 0..63), pre-scaled
    float  Dsel[4];
    f32x4  C0[4];
    {
        bf16x8 B2f[4];
        float c0add[4];
        #pragma unroll
        for (int gi = 0; gi < 4; ++gi) {
            const int n = gi * 64 + w * 16 + n2;
            const float scg = (gi == 2) ? (-2.0f * L2E) : (-L2E);
            #pragma unroll
            for (int kf = 0; kf < 2; ++kf)
                #pragma unroll
                for (int j = 0; j < 8; ++j)
                    Bf[gi][kf][j] = f2bf(Wh[(kf * 32 + q * 8 + j) * 256 + n] * scg);
            #pragma unroll
            for (int j = 0; j < 8; ++j)
                B2f[gi][j] = f2bf(Bx[(q * 8 + j) * 256 + n]);
            c0add[gi] = Bx[32 * 256 + n] + Bx[34 * 256 + n];
            Dsel[gi]  = Bx[33 * 256 + n] - Bx[32 * 256 + n];
        }
        // Atv static A-frag; NEW dup pattern: A row -> batch (row>>2)
        const float g_a = g[wgb + ((l >> 2) & 3)];
        bf16x8 Atv;
        #pragma unroll
        for (int j = 0; j < 8; ++j) {
            int k = q * 8 + j;
            Atv[j] = f2bf(tanhf(g_a * W_g1[k] + b_g1[k]));
        }
        const f32x4 zero4 = {0.f, 0.f, 0.f, 0.f};
        #pragma unroll
        for (int gi = 0; gi < 4; ++gi) {
            C0[gi] = __builtin_amdgcn_mfma_f32_16x16x32_bf16(Atv, B2f[gi], zero4, 0, 0, 0);
            #pragma unroll
            for (int r = 0; r < 4; ++r) C0[gi][r] += c0add[gi];
        }
    }
    // logit DIFF column frags (col 0 = W_amp[:,1]-W_amp[:,0]; others 0) — NOT scaled
    bf16x8 BLd0, BLd1;
    f32x4 CL0;
    {
        #pragma unroll
        for (int j = 0; j < 8; ++j) {
            int k = q * 8 + j;
            BLd0[j] = (n2 == 0) ? f2bf(W_amp[k * 2 + 1] - W_amp[k * 2]) : (short)0;
            BLd1[j] = (n2 == 0) ? f2bf(W_amp[(k + 32) * 2 + 1] - W_amp[(k + 32) * 2]) : (short)0;
        }
        float bd = (n2 == 0) ? (b_amp[1] - b_amp[0]) : 0.f;
        CL0[0] = bd; CL0[1] = bd; CL0[2] = bd; CL0[3] = bd;
    }

    // ---------- state init ----------
    const int fcol  = w * 16 + n2;   // gate-phase f ownership
    const int haddr = q * 80 + fcol; // gate-phase b ownership = q
    float cst;
    {
        float gb = g[wgb + q];
        cst = gb * W_gc[fcol] + b_gc[fcol];
        Hb[0][haddr] = f2bf(gb * W_gh[fcol] + b_gh[fcol]);
    }
    __syncthreads();

    // ---------- main recurrence ----------
    const int ra = ((l >> 2) & 3) * 80 + q * 8;   // A-frag read: batch (l>>2)&3, feats q*8..+8
    float slp = 0.f;
    unsigned spt = 0;                              // sp_l[0]

    auto step = [&](int t, int rb, bool doGate) {
        bf16x8 a0 = *(const bf16x8*)&Hb[rb][ra];
        bf16x8 a1 = *(const bf16x8*)&Hb[rb][ra + 32];
        unsigned spt_n = sp_l[t + 1];             // prefetch next token byte
        const unsigned bit = (spt >> q) & 1u;     // this lane-group's batch token
        const float f_lane = (float)bit;

        f32x4 acc[4];
        #pragma unroll
        for (int gi = 0; gi < 4; ++gi) {
            f32x4 a;
            #pragma unroll
            for (int r = 0; r < 4; ++r)
                a[r] = __builtin_fmaf(f_lane, Dsel[gi], C0[gi][r]);
            a = __builtin_amdgcn_mfma_f32_16x16x32_bf16(a1, Bf[gi][1], a, 0, 0, 0);
            acc[gi] = __builtin_amdgcn_mfma_f32_16x16x32_bf16(a0, Bf[gi][0], a, 0, 0, 0);
        }

        const bool rr = (t >= 1) && (w == (t & 3));
        float dL = 0.f;
        if (rr) {
            f32x4 aL = __builtin_amdgcn_mfma_f32_16x16x32_bf16(a1, BLd1, CL0, 0, 0, 0);
            aL = __builtin_amdgcn_mfma_f32_16x16x32_bf16(a0, BLd0, aL, 0, 0, 0);
            dL = aL[0];
        }

        if (doGate) {
            // y's are already -L2E*z (or -2*L2E*z for gate g)
            const float yi = acc[0][0], yf = acc[1][0], yg = acc[2][0], yo = acc[3][0];
            float si = __builtin_amdgcn_rcpf(1.0f + __builtin_amdgcn_exp2f(yi));
            float sf = __builtin_amdgcn_rcpf(1.0f + __builtin_amdgcn_exp2f(yf));
            float so = __builtin_amdgcn_rcpf(1.0f + __builtin_amdgcn_exp2f(yo));
            float tg = 2.0f * __builtin_amdgcn_rcpf(1.0f + __builtin_amdgcn_exp2f(yg)) - 1.0f;
            float c  = sf * cst + si * tg;
            cst = c;
            float th = 2.0f * __builtin_amdgcn_rcpf(1.0f + __builtin_amdgcn_exp2f(-2.0f * L2E * c)) - 1.0f;
            float h  = so * th;
            unsigned hv;
            asm("v_cvt_pk_bf16_f32 %0, %1, %2" : "=v"(hv) : "v"(h), "v"(h));
            Hb[1 - rb][haddr] = (short)hv;
        }
        spt = spt_n;
        __syncthreads();

        if (rr) {   // post-barrier: overlaps other waves' next-step MFMAs
            float x = bit ? -dL : dL;             // l_token_other - l_token
            float e = __builtin_amdgcn_exp2f(L2E * x);
            slp -= LN2 * __builtin_amdgcn_logf(1.0f + e);
        }
    };

    for (int t2 = 0; t2 < 256; t2 += 2) {
        step(t2, 0, true);
        step(t2 + 1, 1, true);
    }
    step(256, 0, false);   // final logit step, no gate phase

    // ---------- epilogue ----------
    if (n2 == 0) red[w][q] = slp;   // lanes 0,16,32,48 hold batch q partials
    __syncthreads();
    if (tid < 4)
        out[wgb + tid] = red[0][tid] + red[1][tid] + red[2][tid] + red[3][tid];
}

extern "C" void kernel_launch(void* const* d_in, const int* in_sizes, int n_in,
                              void* d_out, int out_size, void* d_ws, size_t ws_size,
                              hipStream_t stream) {
    (void)in_sizes; (void)n_in; (void)out_size; (void)d_ws; (void)ws_size;
    const int*   s      = (const int*)d_in[0];
    const float* g      = (const float*)d_in[1];
    const float* W_emb  = (const float*)d_in[2];
    const float* b_emb  = (const float*)d_in[3];
    const float* W_g1   = (const float*)d_in[4];
    const float* b_g1   = (const float*)d_in[5];
    const float* W_g2   = (const float*)d_in[6];
    const float* b_g2   = (const float*)d_in[7];
    const float* W_gh   = (const float*)d_in[8];
    const float* b_gh   = (const float*)d_in[9];
    const float* W_gc   = (const float*)d_in[10];
    const float* b_gc   = (const float*)d_in[11];
    const float* Wi     = (const float*)d_in[12];
    const float* Wh     = (const float*)d_in[13];
    const float* b_lstm = (const float*)d_in[14];
    const float* W_amp  = (const float*)d_in[15];
    const float* b_amp  = (const float*)d_in[16];
    float* out = (float*)d_out;

    lstm_kernel<<<512, 256, 0, stream>>>(s, g, W_emb, b_emb, W_g1, b_g1, W_g2, b_g2,
                                         W_gh, b_gh, W_gc, b_gc, Wi, Wh, b_lstm,
                                         W_amp, b_amp, out);
}

// Round 2
// 200.125 us; speedup vs baseline: 1.2878x; 1.1649x over previous
//
#include <hip/hip_runtime.h>

// LSTM RNN: B=2048, L=256 (257 scan steps), F=64, H=32, K=2.
// R4: static MFMA C-input. A-rows are 4x dup'd -> all 4 acc elements equal and
//     gates read only element 0, so the token term (bit*Dsel) moves out of the
//     C-init (was 16 fma/step) to a single post-MFMA v_fmac per gate (4 total).
//     C-init is a fully static broadcast C0b[gi] (token-free).
//     Cell state kept pre-scaled: cs = -2*log2e*c, so tanh(c) needs no input
//     multiply: th = 2*rcp(1+exp2(cs))-1.  x4 unroll: rb + rr-wave slot-static.
// h exchange: 640B double buffer, b-stride 160B (<=2-way banks, 16B aligned).

typedef __attribute__((ext_vector_type(8))) short bf16x8;
typedef __attribute__((ext_vector_type(4))) float f32x4;

#define L2E 1.44269504088896340736f
#define LN2 0.69314718055994530942f

__device__ __forceinline__ short f2bf(float x) {
    unsigned u = __builtin_bit_cast(unsigned, x);
    unsigned r = (u + 0x7FFFu + ((u >> 16) & 1u)) >> 16;
    return (short)r;
}

__global__ __launch_bounds__(256) void lstm_kernel(
    const int* __restrict__ s, const float* __restrict__ g,
    const float* __restrict__ W_emb, const float* __restrict__ b_emb,
    const float* __restrict__ W_g1, const float* __restrict__ b_g1,
    const float* __restrict__ W_g2, const float* __restrict__ b_g2,
    const float* __restrict__ W_gh, const float* __restrict__ b_gh,
    const float* __restrict__ W_gc, const float* __restrict__ b_gc,
    const float* __restrict__ Wi, const float* __restrict__ Wh,
    const float* __restrict__ b_lstm, const float* __restrict__ W_amp,
    const float* __restrict__ b_amp, float* __restrict__ out)
{
    __shared__ float Bx[35 * 256];              // 0-31: W_g2@Wi; 32-33: W_emb@Wi; 34: const (pre-scaled)
    __shared__ unsigned char sp_l[260];         // packed tokens: bit b of sp_l[t] = s_pad[b][t]
    __shared__ __align__(16) short Hb[2][320];  // h dbuf: [b(4) * 80 + f(64)] bf16
    __shared__ float red[4][4];                 // per-wave logp partials

    const int tid = threadIdx.x;
    const int w   = tid >> 6;     // wave 0..3
    const int l   = tid & 63;     // lane
    const int n2  = l & 15;       // MFMA col
    const int q   = l >> 4;       // MFMA k-quad == owned batch row
    const int wgb = blockIdx.x * 4;

    // ---------- Setup: folded B rows into LDS, pre-scaled by activation constants ----------
    {
        const int n = tid;
        // cols [0,64)=i, [64,128)=f: sigmoid -> -L2E; [128,192)=g: tanh -> -2*L2E; [192,256)=o: -L2E
        const float sc = (n >= 128 && n < 192) ? (-2.0f * L2E) : (-L2E);
        float acc[35];
        #pragma unroll
        for (int i = 0; i < 35; ++i) acc[i] = 0.f;
        for (int f = 0; f < 64; ++f) {
            float wi = Wi[f * 256 + n] * sc;
            #pragma unroll
            for (int k = 0; k < 32; ++k) acc[k] += W_g2[k * 64 + f] * wi;  // uniform
            acc[32] += W_emb[f] * wi;
            acc[33] += W_emb[64 + f] * wi;
            acc[34] += (b_emb[f] + b_g2[f]) * wi;
        }
        acc[34] += b_lstm[n] * sc;
        #pragma unroll
        for (int i = 0; i < 35; ++i) Bx[i * 256 + n] = acc[i];
    }
    // token staging: sp_l[t+1] bits = s[:, t], sp_l[0] = 0
    {
        unsigned v = 0;
        #pragma unroll
        for (int b = 0; b < 4; ++b)
            v |= (unsigned)(s[(wgb + b) * 256 + tid] & 1) << b;
        sp_l[tid + 1] = (unsigned char)v;
        if (tid == 0) sp_l[0] = 0;
    }
    __syncthreads();

    // ---------- static fragments ----------
    bf16x8 Bf[4][2];          // Wh (K 0..63), pre-scaled
    float  Dsel[4];
    f32x4  C0b[4];            // STATIC broadcast C-init (token-free); all 4 elems equal
    {
        bf16x8 B2f[4];
        float c0add[4];
        #pragma unroll
        for (int gi = 0; gi < 4; ++gi) {
            const int n = gi * 64 + w * 16 + n2;
            const float scg = (gi == 2) ? (-2.0f * L2E) : (-L2E);
            #pragma unroll
            for (int kf = 0; kf < 2; ++kf)
                #pragma unroll
                for (int j = 0; j < 8; ++j)
                    Bf[gi][kf][j] = f2bf(Wh[(kf * 32 + q * 8 + j) * 256 + n] * scg);
            #pragma unroll
            for (int j = 0; j < 8; ++j)
                B2f[gi][j] = f2bf(Bx[(q * 8 + j) * 256 + n]);
            c0add[gi] = Bx[32 * 256 + n] + Bx[34 * 256 + n];
            Dsel[gi]  = Bx[33 * 256 + n] - Bx[32 * 256 + n];
        }
        // Atv static A-frag; dup pattern: A row -> batch (row>>2)
        const float g_a = g[wgb + ((l >> 2) & 3)];
        bf16x8 Atv;
        #pragma unroll
        for (int j = 0; j < 8; ++j) {
            int k = q * 8 + j;
            Atv[j] = f2bf(tanhf(g_a * W_g1[k] + b_g1[k]));
        }
        const f32x4 zero4 = {0.f, 0.f, 0.f, 0.f};
        #pragma unroll
        for (int gi = 0; gi < 4; ++gi) {
            f32x4 c = __builtin_amdgcn_mfma_f32_16x16x32_bf16(Atv, B2f[gi], zero4, 0, 0, 0);
            float cv = c[0] + c0add[gi];   // rows identical -> element 0 is the value
            C0b[gi][0] = cv; C0b[gi][1] = cv; C0b[gi][2] = cv; C0b[gi][3] = cv;
        }
    }
    // logit DIFF column frags (col 0 = W_amp[:,1]-W_amp[:,0]; others 0) — NOT scaled
    bf16x8 BLd0, BLd1;
    f32x4 CL0;
    {
        #pragma unroll
        for (int j = 0; j < 8; ++j) {
            int k = q * 8 + j;
            BLd0[j] = (n2 == 0) ? f2bf(W_amp[k * 2 + 1] - W_amp[k * 2]) : (short)0;
            BLd1[j] = (n2 == 0) ? f2bf(W_amp[(k + 32) * 2 + 1] - W_amp[(k + 32) * 2]) : (short)0;
        }
        float bd = (n2 == 0) ? (b_amp[1] - b_amp[0]) : 0.f;
        CL0[0] = bd; CL0[1] = bd; CL0[2] = bd; CL0[3] = bd;
    }

    // ---------- state init (cell state kept pre-scaled: cs = -2*L2E*c) ----------
    const int fcol  = w * 16 + n2;   // gate-phase f ownership
    const int haddr = q * 80 + fcol; // gate-phase b ownership = q
    float cs;
    {
        float gb = g[wgb + q];
        cs = (-2.0f * L2E) * (gb * W_gc[fcol] + b_gc[fcol]);
        Hb[0][haddr] = f2bf(gb * W_gh[fcol] + b_gh[fcol]);
    }
    __syncthreads();

    // ---------- main recurrence ----------
    const int ra = ((l >> 2) & 3) * 80 + q * 8;   // A-frag read: batch (l>>2)&3, feats q*8..+8
    float slp = 0.f;
    unsigned spt = 0;                              // sp_l[0]

    auto step = [&](int t, int rb, int slot, bool doGate) {
        bf16x8 a0 = *(const bf16x8*)&Hb[rb][ra];
        bf16x8 a1 = *(const bf16x8*)&Hb[rb][ra + 32];
        unsigned spt_n = sp_l[t + 1];             // prefetch next token byte
        const unsigned bit = (spt >> q) & 1u;     // this lane-group's batch token (s_pad[t])
        const float f_lane = (float)bit;

        f32x4 acc[4];
        #pragma unroll
        for (int gi = 0; gi < 4; ++gi) {
            f32x4 a = __builtin_amdgcn_mfma_f32_16x16x32_bf16(a1, Bf[gi][1], C0b[gi], 0, 0, 0);
            acc[gi] = __builtin_amdgcn_mfma_f32_16x16x32_bf16(a0, Bf[gi][0], a, 0, 0, 0);
        }

        const bool rr = (w == slot) && (t >= 1);  // slot-static round-robin logit wave
        float dL = 0.f;
        if (rr) {
            f32x4 aL = __builtin_amdgcn_mfma_f32_16x16x32_bf16(a1, BLd1, CL0, 0, 0, 0);
            aL = __builtin_amdgcn_mfma_f32_16x16x32_bf16(a0, BLd0, aL, 0, 0, 0);
            dL = aL[0];
        }

        if (doGate) {
            // token fold: only element 0 is consumed -> 1 fmac per gate
            float yi = __builtin_fmaf(f_lane, Dsel[0], acc[0][0]);
            float yf = __builtin_fmaf(f_lane, Dsel[1], acc[1][0]);
            float yg = __builtin_fmaf(f_lane, Dsel[2], acc[2][0]);
            float yo = __builtin_fmaf(f_lane, Dsel[3], acc[3][0]);
            // y's are -L2E*z (i,f,o) and -2*L2E*z (g)
            float si = __builtin_amdgcn_rcpf(1.0f + __builtin_amdgcn_exp2f(yi));
            float sf = __builtin_amdgcn_rcpf(1.0f + __builtin_amdgcn_exp2f(yf));
            float rg = __builtin_amdgcn_rcpf(1.0f + __builtin_amdgcn_exp2f(yg));
            float so = __builtin_amdgcn_rcpf(1.0f + __builtin_amdgcn_exp2f(yo));
            float tgs = __builtin_fmaf(-4.0f * L2E, rg, 2.0f * L2E);   // = -2*L2E*tanh(zg)
            cs = __builtin_fmaf(sf, cs, si * tgs);                      // cs' = -2*L2E*c'
            float r5 = __builtin_amdgcn_rcpf(1.0f + __builtin_amdgcn_exp2f(cs));
            float th = __builtin_fmaf(2.0f, r5, -1.0f);                 // tanh(c')
            float h  = so * th;
            unsigned hv;
            asm("v_cvt_pk_bf16_f32 %0, %1, %2" : "=v"(hv) : "v"(h), "v"(h));
            Hb[1 - rb][haddr] = (short)hv;
        }
        const unsigned bitc = bit;
        spt = spt_n;
        __syncthreads();

        if (rr) {   // post-barrier: overlaps other waves' next-step MFMAs
            float x = bitc ? -dL : dL;            // l_token_other - l_token
            float e = __builtin_amdgcn_exp2f(L2E * x);
            slp -= LN2 * __builtin_amdgcn_logf(1.0f + e);
        }
    };

    for (int t0 = 0; t0 < 256; t0 += 4) {
        step(t0 + 0, 0, 0, true);
        step(t0 + 1, 1, 1, true);
        step(t0 + 2, 0, 2, true);
        step(t0 + 3, 1, 3, true);
    }
    step(256, 0, 0, false);   // final logit step, no gate phase

    // ---------- epilogue ----------
    if (n2 == 0) red[w][q] = slp;   // lanes 0,16,32,48 hold batch q partials
    __syncthreads();
    if (tid < 4)
        out[wgb + tid] = red[0][tid] + red[1][tid] + red[2][tid] + red[3][tid];
}

extern "C" void kernel_launch(void* const* d_in, const int* in_sizes, int n_in,
                              void* d_out, int out_size, void* d_ws, size_t ws_size,
                              hipStream_t stream) {
    (void)in_sizes; (void)n_in; (void)out_size; (void)d_ws; (void)ws_size;
    const int*   s      = (const int*)d_in[0];
    const float* g      = (const float*)d_in[1];
    const float* W_emb  = (const float*)d_in[2];
    const float* b_emb  = (const float*)d_in[3];
    const float* W_g1   = (const float*)d_in[4];
    const float* b_g1   = (const float*)d_in[5];
    const float* W_g2   = (const float*)d_in[6];
    const float* b_g2   = (const float*)d_in[7];
    const float* W_gh   = (const float*)d_in[8];
    const float* b_gh   = (const float*)d_in[9];
    const float* W_gc   = (const float*)d_in[10];
    const float* b_gc   = (const float*)d_in[11];
    const float* Wi     = (const float*)d_in[12];
    const float* Wh     = (const float*)d_in[13];
    const float* b_lstm = (const float*)d_in[14];
    const float* W_amp  = (const float*)d_in[15];
    const float* b_amp  = (const float*)d_in[16];
    float* out = (float*)d_out;

    lstm_kernel<<<512, 256, 0, stream>>>(s, g, W_emb, b_emb, W_g1, b_g1, W_g2, b_g2,
                                         W_gh, b_gh, W_gc, b_gc, Wi, Wh, b_lstm,
                                         W_amp, b_amp, out);
}

// Round 3
// 195.493 us; speedup vs baseline: 1.3184x; 1.0237x over previous
//
#include <hip/hip_runtime.h>

// LSTM RNN: B=2048, L=256 (257 scan steps), F=64, H=32, K=2.
// R5: 256 wgs x 8 batch rows, 1 wg/CU. A-rows dup x2 (batch = row>>1) instead
//     of x4 -> chip-wide MFMA work halves (8 MFMA/wave/step now covers 8
//     batches). 2 states per thread (acc regs 0 and 2), independent -> ILP
//     fills trans latency in the 1-wave/SIMD regime. One barrier per step per
//     CU instead of two interleaved wgs. Single v_cvt_pk converts both h's.
//     Gate cols pre-scaled by -L2E (i,f,o) / -2*L2E (g); cs = -2*L2E*c kept
//     pre-scaled. x4 unroll: rb + rr logit wave slot-static.
// h exchange: 8x80-short double buffer (160B batch stride, 16B aligned).

typedef __attribute__((ext_vector_type(8))) short bf16x8;
typedef __attribute__((ext_vector_type(4))) float f32x4;

#define L2E 1.44269504088896340736f
#define LN2 0.69314718055994530942f

__device__ __forceinline__ short f2bf(float x) {
    unsigned u = __builtin_bit_cast(unsigned, x);
    unsigned r = (u + 0x7FFFu + ((u >> 16) & 1u)) >> 16;
    return (short)r;
}

__global__ __launch_bounds__(256, 1) void lstm_kernel(
    const int* __restrict__ s, const float* __restrict__ g,
    const float* __restrict__ W_emb, const float* __restrict__ b_emb,
    const float* __restrict__ W_g1, const float* __restrict__ b_g1,
    const float* __restrict__ W_g2, const float* __restrict__ b_g2,
    const float* __restrict__ W_gh, const float* __restrict__ b_gh,
    const float* __restrict__ W_gc, const float* __restrict__ b_gc,
    const float* __restrict__ Wi, const float* __restrict__ Wh,
    const float* __restrict__ b_lstm, const float* __restrict__ W_amp,
    const float* __restrict__ b_amp, float* __restrict__ out)
{
    __shared__ float Bx[35 * 256];              // 0-31: W_g2@Wi; 32-33: W_emb@Wi; 34: const (pre-scaled)
    __shared__ unsigned char sp_l[260];         // packed tokens: bit b of sp_l[t] = s_pad[b][t], 8 batches
    __shared__ __align__(16) short Hb[2][640];  // h dbuf: [b(8) * 80 + f(64)] bf16
    __shared__ float red[4][8];                 // per-wave logp partials

    const int tid = threadIdx.x;
    const int w   = tid >> 6;     // wave 0..3
    const int l   = tid & 63;     // lane
    const int n2  = l & 15;       // MFMA col
    const int q   = l >> 4;       // MFMA k-quad
    const int wgb = blockIdx.x * 8;

    // ---------- Setup: folded B rows into LDS, pre-scaled by activation constants ----------
    {
        const int n = tid;
        // cols [0,64)=i, [64,128)=f: sigmoid -> -L2E; [128,192)=g: tanh -> -2*L2E; [192,256)=o: -L2E
        const float sc = (n >= 128 && n < 192) ? (-2.0f * L2E) : (-L2E);
        float acc[35];
        #pragma unroll
        for (int i = 0; i < 35; ++i) acc[i] = 0.f;
        for (int f = 0; f < 64; ++f) {
            float wi = Wi[f * 256 + n] * sc;
            #pragma unroll
            for (int k = 0; k < 32; ++k) acc[k] += W_g2[k * 64 + f] * wi;  // uniform
            acc[32] += W_emb[f] * wi;
            acc[33] += W_emb[64 + f] * wi;
            acc[34] += (b_emb[f] + b_g2[f]) * wi;
        }
        acc[34] += b_lstm[n] * sc;
        #pragma unroll
        for (int i = 0; i < 35; ++i) Bx[i * 256 + n] = acc[i];
    }
    // token staging: sp_l[t+1] bits = s[:, t] for 8 batch rows, sp_l[0] = 0
    {
        unsigned v = 0;
        #pragma unroll
        for (int b = 0; b < 8; ++b)
            v |= (unsigned)(s[(wgb + b) * 256 + tid] & 1) << b;
        sp_l[tid + 1] = (unsigned char)v;
        if (tid == 0) sp_l[0] = 0;
    }
    __syncthreads();

    // ---------- static fragments ----------
    bf16x8 Bf[4][2];          // Wh (K 0..63), pre-scaled
    float  Dsel[4];
    f32x4  C0b[4];            // STATIC C-init; elems {0,1}=batch 2q, {2,3}=batch 2q+1
    {
        bf16x8 B2f[4];
        float c0add[4];
        #pragma unroll
        for (int gi = 0; gi < 4; ++gi) {
            const int n = gi * 64 + w * 16 + n2;
            const float scg = (gi == 2) ? (-2.0f * L2E) : (-L2E);
            #pragma unroll
            for (int kf = 0; kf < 2; ++kf)
                #pragma unroll
                for (int j = 0; j < 8; ++j)
                    Bf[gi][kf][j] = f2bf(Wh[(kf * 32 + q * 8 + j) * 256 + n] * scg);
            #pragma unroll
            for (int j = 0; j < 8; ++j)
                B2f[gi][j] = f2bf(Bx[(q * 8 + j) * 256 + n]);
            c0add[gi] = Bx[32 * 256 + n] + Bx[34 * 256 + n];
            Dsel[gi]  = Bx[33 * 256 + n] - Bx[32 * 256 + n];
        }
        // Atv static A-frag; dup pattern: A row r -> batch r>>1
        const float g_a = g[wgb + ((l & 15) >> 1)];
        bf16x8 Atv;
        #pragma unroll
        for (int j = 0; j < 8; ++j) {
            int k = q * 8 + j;
            Atv[j] = f2bf(tanhf(g_a * W_g1[k] + b_g1[k]));
        }
        const f32x4 zero4 = {0.f, 0.f, 0.f, 0.f};
        #pragma unroll
        for (int gi = 0; gi < 4; ++gi) {
            f32x4 c = __builtin_amdgcn_mfma_f32_16x16x32_bf16(Atv, B2f[gi], zero4, 0, 0, 0);
            float cvA = c[0] + c0add[gi];   // rows q*4+{0,1} -> batch 2q
            float cvB = c[2] + c0add[gi];   // rows q*4+{2,3} -> batch 2q+1
            C0b[gi][0] = cvA; C0b[gi][1] = cvA; C0b[gi][2] = cvB; C0b[gi][3] = cvB;
        }
    }
    // logit DIFF column frags (col 0 = W_amp[:,1]-W_amp[:,0]; others 0) — NOT scaled
    bf16x8 BLd0, BLd1;
    f32x4 CL0;
    {
        #pragma unroll
        for (int j = 0; j < 8; ++j) {
            int k = q * 8 + j;
            BLd0[j] = (n2 == 0) ? f2bf(W_amp[k * 2 + 1] - W_amp[k * 2]) : (short)0;
            BLd1[j] = (n2 == 0) ? f2bf(W_amp[(k + 32) * 2 + 1] - W_amp[(k + 32) * 2]) : (short)0;
        }
        float bd = (n2 == 0) ? (b_amp[1] - b_amp[0]) : 0.f;
        CL0[0] = bd; CL0[1] = bd; CL0[2] = bd; CL0[3] = bd;
    }

    // ---------- state init (cs = -2*L2E*c, pre-scaled) ----------
    const int fcol   = w * 16 + n2;      // gate-phase f ownership
    const int bA     = q * 2;            // gate-phase batches (MFMA rows q*4+{0,1} / {2,3})
    const int bB     = bA + 1;
    const int haddrA = bA * 80 + fcol;
    const int haddrB = haddrA + 80;
    float csA, csB;
    {
        float gA = g[wgb + bA], gB = g[wgb + bB];
        csA = (-2.0f * L2E) * (gA * W_gc[fcol] + b_gc[fcol]);
        csB = (-2.0f * L2E) * (gB * W_gc[fcol] + b_gc[fcol]);
        Hb[0][haddrA] = f2bf(gA * W_gh[fcol] + b_gh[fcol]);
        Hb[0][haddrB] = f2bf(gB * W_gh[fcol] + b_gh[fcol]);
    }
    __syncthreads();

    // ---------- main recurrence ----------
    const int ra = ((l & 15) >> 1) * 80 + q * 8;   // A-frag: batch (l&15)>>1, feats q*8..+8
    float slpA = 0.f, slpB = 0.f;
    unsigned spt = 0;                              // sp_l[0]

    auto step = [&](int t, int rb, int slot, bool doGate) {
        bf16x8 a0 = *(const bf16x8*)&Hb[rb][ra];
        bf16x8 a1 = *(const bf16x8*)&Hb[rb][ra + 32];
        unsigned spt_n = sp_l[t + 1];             // prefetch next token byte
        const unsigned bitA = (spt >> bA) & 1u;   // tokens s_pad[t] for this thread's batches
        const unsigned bitB = (spt >> bB) & 1u;
        const float fA = (float)bitA, fB = (float)bitB;

        f32x4 acc[4];
        #pragma unroll
        for (int gi = 0; gi < 4; ++gi) {
            f32x4 a = __builtin_amdgcn_mfma_f32_16x16x32_bf16(a1, Bf[gi][1], C0b[gi], 0, 0, 0);
            acc[gi] = __builtin_amdgcn_mfma_f32_16x16x32_bf16(a0, Bf[gi][0], a, 0, 0, 0);
        }

        const bool rr = (w == slot) && (t >= 1);  // slot-static round-robin logit wave
        float dLA = 0.f, dLB = 0.f;
        if (rr) {
            f32x4 aL = __builtin_amdgcn_mfma_f32_16x16x32_bf16(a1, BLd1, CL0, 0, 0, 0);
            aL = __builtin_amdgcn_mfma_f32_16x16x32_bf16(a0, BLd0, aL, 0, 0, 0);
            dLA = aL[0]; dLB = aL[2];
        }

        if (doGate) {
            // state A (acc elem 0), state B (acc elem 2) — independent chains (ILP)
            float yiA = __builtin_fmaf(fA, Dsel[0], acc[0][0]);
            float yiB = __builtin_fmaf(fB, Dsel[0], acc[0][2]);
            float yfA = __builtin_fmaf(fA, Dsel[1], acc[1][0]);
            float yfB = __builtin_fmaf(fB, Dsel[1], acc[1][2]);
            float ygA = __builtin_fmaf(fA, Dsel[2], acc[2][0]);
            float ygB = __builtin_fmaf(fB, Dsel[2], acc[2][2]);
            float yoA = __builtin_fmaf(fA, Dsel[3], acc[3][0]);
            float yoB = __builtin_fmaf(fB, Dsel[3], acc[3][2]);
            float siA = __builtin_amdgcn_rcpf(1.0f + __builtin_amdgcn_exp2f(yiA));
            float siB = __builtin_amdgcn_rcpf(1.0f + __builtin_amdgcn_exp2f(yiB));
            float sfA = __builtin_amdgcn_rcpf(1.0f + __builtin_amdgcn_exp2f(yfA));
            float sfB = __builtin_amdgcn_rcpf(1.0f + __builtin_amdgcn_exp2f(yfB));
            float rgA = __builtin_amdgcn_rcpf(1.0f + __builtin_amdgcn_exp2f(ygA));
            float rgB = __builtin_amdgcn_rcpf(1.0f + __builtin_amdgcn_exp2f(ygB));
            float soA = __builtin_amdgcn_rcpf(1.0f + __builtin_amdgcn_exp2f(yoA));
            float soB = __builtin_amdgcn_rcpf(1.0f + __builtin_amdgcn_exp2f(yoB));
            float tgsA = __builtin_fmaf(-4.0f * L2E, rgA, 2.0f * L2E);   // -2*L2E*tanh(zg)
            float tgsB = __builtin_fmaf(-4.0f * L2E, rgB, 2.0f * L2E);
            csA = __builtin_fmaf(sfA, csA, siA * tgsA);
            csB = __builtin_fmaf(sfB, csB, siB * tgsB);
            float r5A = __builtin_amdgcn_rcpf(1.0f + __builtin_amdgcn_exp2f(csA));
            float r5B = __builtin_amdgcn_rcpf(1.0f + __builtin_amdgcn_exp2f(csB));
            float thA = __builtin_fmaf(2.0f, r5A, -1.0f);
            float thB = __builtin_fmaf(2.0f, r5B, -1.0f);
            float hA  = soA * thA;
            float hB  = soB * thB;
            unsigned hv;
            asm("v_cvt_pk_bf16_f32 %0, %1, %2" : "=v"(hv) : "v"(hA), "v"(hB));
            Hb[1 - rb][haddrA] = (short)hv;
            Hb[1 - rb][haddrB] = (short)(hv >> 16);
        }
        const unsigned bAc = bitA, bBc = bitB;
        spt = spt_n;
        __syncthreads();

        if (rr) {   // post-barrier: overlaps other waves' next-step MFMAs
            float xA = bAc ? -dLA : dLA;          // l_token_other - l_token
            float xB = bBc ? -dLB : dLB;
            float eA = __builtin_amdgcn_exp2f(L2E * xA);
            float eB = __builtin_amdgcn_exp2f(L2E * xB);
            slpA -= LN2 * __builtin_amdgcn_logf(1.0f + eA);
            slpB -= LN2 * __builtin_amdgcn_logf(1.0f + eB);
        }
    };

    for (int t0 = 0; t0 < 256; t0 += 4) {
        step(t0 + 0, 0, 0, true);
        step(t0 + 1, 1, 1, true);
        step(t0 + 2, 0, 2, true);
        step(t0 + 3, 1, 3, true);
    }
    step(256, 0, 0, false);   // final logit step, no gate phase

    // ---------- epilogue ----------
    if (n2 == 0) { red[w][bA] = slpA; red[w][bB] = slpB; }  // lanes 0,16,32,48
    __syncthreads();
    if (tid < 8)
        out[wgb + tid] = red[0][tid] + red[1][tid] + red[2][tid] + red[3][tid];
}

extern "C" void kernel_launch(void* const* d_in, const int* in_sizes, int n_in,
                              void* d_out, int out_size, void* d_ws, size_t ws_size,
                              hipStream_t stream) {
    (void)in_sizes; (void)n_in; (void)out_size; (void)d_ws; (void)ws_size;
    const int*   s      = (const int*)d_in[0];
    const float* g      = (const float*)d_in[1];
    const float* W_emb  = (const float*)d_in[2];
    const float* b_emb  = (const float*)d_in[3];
    const float* W_g1   = (const float*)d_in[4];
    const float* b_g1   = (const float*)d_in[5];
    const float* W_g2   = (const float*)d_in[6];
    const float* b_g2   = (const float*)d_in[7];
    const float* W_gh   = (const float*)d_in[8];
    const float* b_gh   = (const float*)d_in[9];
    const float* W_gc   = (const float*)d_in[10];
    const float* b_gc   = (const float*)d_in[11];
    const float* Wi     = (const float*)d_in[12];
    const float* Wh     = (const float*)d_in[13];
    const float* b_lstm = (const float*)d_in[14];
    const float* W_amp  = (const float*)d_in[15];
    const float* b_amp  = (const float*)d_in[16];
    float* out = (float*)d_out;

    lstm_kernel<<<256, 256, 0, stream>>>(s, g, W_emb, b_emb, W_g1, b_g1, W_g2, b_g2,
                                         W_gh, b_gh, W_gc, b_gc, Wi, Wh, b_lstm,
                                         W_amp, b_amp, out);
}